// Round 5
// baseline (185.587 us; speedup 1.0000x reference)
//
#include <hip/hip_runtime.h>
#include <hip/hip_bf16.h>

// TreeCnnLayer: y[b,l,o] = relu( sum_{k=0..3} x[b, idx[l,k], :] . mask[k,:,o] + bias[127] )
// == GEMM: A[131072 x 512] (gathered, fp32->bf16) * Bm[512 x 128] (mask), fp32 out.
//
// R5: R4 was latency-bound (occ 15.6%, all pipes <16%): 64KiB LDS capped 2 blocks/CU and
// every tile barrier-drained the itab->gather dependent chain. New structure: NO LDS, NO
// barriers. Each wave owns one 16-col group (B = 16 short8 = 64 VGPR resident) and loads
// its A fragments directly global->VGPR (fp32, cvt_pk on the fly). A is re-read once per
// colgrp (8x) - L2/L3-side only, HBM still reads x once. 12 free-running waves/CU hide
// the gather latency; next row-tile's int4 index is prefetched under current MFMAs.

namespace {

constexpr int kNodes = 8192;        // n+1
constexpr int kIn = 128;
constexpr int kOut = 128;
constexpr int kThreads = 256;       // 4 waves
constexpr int kGrid = 1024;         // 512 row-ranges x 2 col-halves
constexpr int kTiles = 16;          // 16-node tiles per wave -> 256 nodes per range

typedef __attribute__((ext_vector_type(8))) short short8;   // 8 bf16 (MFMA A/B frag)
typedef __attribute__((ext_vector_type(4))) float f32x4;

// bf16 B fragments: [kk(16)][colgrp(8)][lane(64)] of short8 = 128 KiB (L2-resident).
__device__ short8 g_bfrag[16 * 8 * 64];

__device__ __forceinline__ short f2bf(float f) {
  return __builtin_bit_cast(short, __float2bfloat16(f));  // RNE; fuses to v_cvt_pk_bf16_f32
}

// Prep: mask (4,128,128) fp32 -> bf16 MFMA-frag layout (proven R2-R4).
__global__ void prep_bfrag(const float* __restrict__ mask) {
  const int t = blockIdx.x * blockDim.x + threadIdx.x;
  const int kk = t >> 9, g = (t >> 6) & 7, lane = t & 63;
  const int krow = kk * 32 + (lane >> 4) * 8;
  const int col = g * 16 + (lane & 15);
  short8 pk;
#pragma unroll
  for (int e = 0; e < 8; ++e) pk[e] = f2bf(mask[(krow + e) * kOut + col]);
  g_bfrag[t] = pk;
}

__global__ __launch_bounds__(kThreads, 3)
void tree_gemm(const float* __restrict__ x, const float* __restrict__ bias,
               const int* __restrict__ itab, float* __restrict__ y) {
  const int tid  = threadIdx.x;
  const int lane = tid & 63;
  const int wv   = tid >> 6;   // wave 0..3
  const int l15  = lane & 15;
  const int l4   = lane >> 4;  // 0..3

  // XCD-chunked bijective swizzle (1024 % 8 == 0): consecutive sb -> same XCD.
  const int sb    = (blockIdx.x & 7) * (kGrid / 8) + (blockIdx.x >> 3);
  const int range = sb >> 1;                 // 0..511: 256-node span
  const int g     = (sb & 1) * 4 + wv;       // colgrp 0..7 (16 cols each)
  const int bb    = range >> 5;              // batch 0..15
  const int nodeBase = (range & 31) * 256;

  const float* xb = x + (size_t)bb * kNodes * kIn;
  const float blast = bias[kOut - 1];

  // ---- resident B fragments for this wave's colgrp: 64 VGPR ----
  short8 bf[16];
  {
    const short8* gb = g_bfrag + g * 64 + lane;
#pragma unroll
    for (int kk = 0; kk < 16; ++kk) bf[kk] = gb[kk * 512];
  }

  const int4* itab4 = reinterpret_cast<const int4*>(itab);  // [node] -> 4 neighbors

  int4 idx = itab4[nodeBase + l15];  // node (base + l15)'s 4 gather rows
  for (int t = 0; t < kTiles; ++t) {
    // prefetch next tile's indices; lands under this tile's compute
    int4 idxn = idx;
    if (t + 1 < kTiles) idxn = itab4[nodeBase + (t + 1) * 16 + l15];

    const float* a0 = xb + (size_t)idx.x * kIn + l4 * 8;
    const float* a1 = xb + (size_t)idx.y * kIn + l4 * 8;
    const float* a2 = xb + (size_t)idx.z * kIn + l4 * 8;
    const float* a3 = xb + (size_t)idx.w * kIn + l4 * 8;

    f32x4 acc = {};
#pragma unroll
    for (int kk = 0; kk < 16; ++kk) {
      // neighbor c = kk>>2 (compile-time per unrolled kk); 128B chunk (kk&3)
      const float* ap = (kk < 4 ? a0 : kk < 8 ? a1 : kk < 12 ? a2 : a3) + (kk & 3) * 32;
      const f32x4 lo = *reinterpret_cast<const f32x4*>(ap);
      const f32x4 hi = *reinterpret_cast<const f32x4*>(ap + 4);
      short8 a;
      a[0] = f2bf(lo[0]); a[1] = f2bf(lo[1]); a[2] = f2bf(lo[2]); a[3] = f2bf(lo[3]);
      a[4] = f2bf(hi[0]); a[5] = f2bf(hi[1]); a[6] = f2bf(hi[2]); a[7] = f2bf(hi[3]);
      acc = __builtin_amdgcn_mfma_f32_16x16x32_bf16(a, bf[kk], acc, 0, 0, 0);
    }

    // D frag: col = lane&15, row = (lane>>4)*4 + r (m89-verified, matches R2-R4)
    float* yb = y + ((size_t)bb * kNodes + nodeBase + t * 16) * kOut + g * 16 + l15;
#pragma unroll
    for (int r = 0; r < 4; ++r) {
      const float v = acc[r] + blast;
      yb[(l4 * 4 + r) * kOut] = v > 0.f ? v : 0.f;
    }

    idx = idxn;
  }
}

}  // namespace

extern "C" void kernel_launch(void* const* d_in, const int* in_sizes, int n_in,
                              void* d_out, int out_size, void* d_ws, size_t ws_size,
                              hipStream_t stream) {
  const float* x    = (const float*)d_in[0];
  const float* mask = (const float*)d_in[1];
  const float* bias = (const float*)d_in[2];
  const int*   itab = (const int*)d_in[3];
  float*       y    = (float*)d_out;
  (void)in_sizes; (void)n_in; (void)out_size; (void)d_ws; (void)ws_size;

  prep_bfrag<<<dim3(32), dim3(256), 0, stream>>>(mask);
  tree_gemm<<<dim3(kGrid), dim3(kThreads), 0, stream>>>(x, bias, itab, y);
}

// Round 6
// 69.406 us; speedup vs baseline: 2.6739x; 2.6739x over previous
//
#include <hip/hip_runtime.h>
#include <hip/hip_bf16.h>

// TreeCnnLayer: y[b,l,o] = relu( sum_{k=0..3} x[b, idx[l,k], :] . mask[k,:,o] + bias[127] )
// == GEMM: A[131072 x 512] (gathered, fp32->bf16) * Bm[512 x 128] (mask), fp32 out.
//
// R6: R1/R3/R5 all lost to the register allocator (large resident arrays spilled).
// New invariants: (1) B in LDS, filled ONCE per block, single barrier, main loop
// barrier-free; (2) A gathered global->VGPR directly in MFMA frag layout with full
// cache-line utilization (lane=(row l15, kchunk l4)); (3) no register array anywhere.
//  - 512-thr blocks (8 waves); wave = 32 rows x 64 cols (2 rowtiles x 4 colgrps)
//  - block = 512 rows x one col-half; B-LDS = 4 colgrps x 16KiB = 64KiB
//  - grid 512 = exactly 2 blocks/CU resident; launch_bounds(512,4) caps VGPR at 128
//    (genuine live ~85 -> scheduler throttles load-hoisting instead of spilling)

namespace {

constexpr int kNodes = 8192;        // n+1
constexpr int kIn = 128;
constexpr int kOut = 128;
constexpr int kThreads = 512;       // 8 waves
constexpr int kGrid = 512;          // 256 row-chunks x 2 col-halves

typedef __attribute__((ext_vector_type(8))) short short8;   // 8 bf16 (MFMA A/B frag)
typedef __attribute__((ext_vector_type(4))) float f32x4;

// bf16 B fragments: [kk(16)][colgrp(8)][lane(64)] of short8 = 128 KiB (L2-resident).
__device__ short8 g_bfrag[16 * 8 * 64];

__device__ __forceinline__ short f2bf(float f) {
  return __builtin_bit_cast(short, __float2bfloat16(f));  // RNE; fuses to v_cvt_pk_bf16_f32
}

// Prep: mask (4,128,128) fp32 -> bf16 MFMA-frag layout (proven R2-R5).
__global__ void prep_bfrag(const float* __restrict__ mask) {
  const int t = blockIdx.x * blockDim.x + threadIdx.x;
  const int kk = t >> 9, g = (t >> 6) & 7, lane = t & 63;
  const int krow = kk * 32 + (lane >> 4) * 8;
  const int col = g * 16 + (lane & 15);
  short8 pk;
#pragma unroll
  for (int e = 0; e < 8; ++e) pk[e] = f2bf(mask[(krow + e) * kOut + col]);
  g_bfrag[t] = pk;
}

__global__ __launch_bounds__(kThreads, 4)
void tree_gemm(const float* __restrict__ x, const float* __restrict__ bias,
               const int* __restrict__ itab, float* __restrict__ y) {
  // B fragments for this block's 4 colgrps: slot m = kk*4+cg, 64 lanes x 16B each.
  __shared__ __align__(16) short8 ldsB[64 * 64];  // 64 KiB

  const int tid  = threadIdx.x;
  const int lane = tid & 63;
  const int wv   = tid >> 6;   // wave 0..7
  const int l15  = lane & 15;
  const int l4   = lane >> 4;  // 0..3

  // XCD-chunked bijective swizzle (512 % 8 == 0): both col-halves of a row-chunk
  // plus neighboring chunks land on the same XCD L2.
  const int sb      = (blockIdx.x & 7) * (kGrid / 8) + (blockIdx.x >> 3);
  const int colhalf = sb & 1;
  const int rc      = sb >> 1;              // 0..255
  const int batch   = rc >> 4;              // 0..15
  const int node0   = (rc & 15) * 512;      // 512 nodes per chunk

  const float* xb = x + (size_t)batch * kNodes * kIn;

  // ---- fill B-LDS from g_bfrag: 8 slots per wave, 1KB per global_load_lds ----
#pragma unroll
  for (int j = 0; j < 8; ++j) {
    const int m = wv * 8 + j;                       // slot = kk*4 + cg
    const short8* src = &g_bfrag[((m >> 2) * 8 + colhalf * 4 + (m & 3)) * 64 + lane];
    __builtin_amdgcn_global_load_lds(
        (const __attribute__((address_space(1))) void*)src,
        (__attribute__((address_space(3))) void*)&ldsB[m * 64], 16, 0, 0);
  }

  // ---- gather indices for both t-iterations (loaded pre-barrier, flight overlaps) ----
  const int4* itab4 = reinterpret_cast<const int4*>(itab);
  int4 ia[2], ib[2];
#pragma unroll
  for (int t = 0; t < 2; ++t) {
    const int r0 = node0 + wv * 64 + t * 32;
    ia[t] = itab4[r0 + l15];        // rowtile 0: rows r0..r0+15
    ib[t] = itab4[r0 + 16 + l15];   // rowtile 1: rows r0+16..r0+31
  }

  const float blast = bias[kOut - 1];

  __syncthreads();  // ldsB ready; ONLY barrier in the kernel

#pragma unroll
  for (int t = 0; t < 2; ++t) {
    const int rows0 = node0 + wv * 64 + t * 32;
    const int idxa[4] = {ia[t].x, ia[t].y, ia[t].z, ia[t].w};
    const int idxb[4] = {ib[t].x, ib[t].y, ib[t].z, ib[t].w};
    const float* pa[4];
    const float* pb[4];
#pragma unroll
    for (int c = 0; c < 4; ++c) {   // c compile-time under unroll -> ptrs stay in regs
      pa[c] = xb + (size_t)idxa[c] * kIn + l4 * 8;
      pb[c] = xb + (size_t)idxb[c] * kIn + l4 * 8;
    }

    f32x4 acc[2][4] = {};  // [rowtile][colgrp], all indices compile-time
#pragma unroll
    for (int kk = 0; kk < 16; ++kk) {
      const int c = kk >> 2;                 // neighbor (compile-time)
      const float* qa = pa[c] + (kk & 3) * 32;
      const float* qb = pb[c] + (kk & 3) * 32;
      const f32x4 la = *reinterpret_cast<const f32x4*>(qa);
      const f32x4 ha = *reinterpret_cast<const f32x4*>(qa + 4);
      const f32x4 lb = *reinterpret_cast<const f32x4*>(qb);
      const f32x4 hb = *reinterpret_cast<const f32x4*>(qb + 4);
      short8 fa, fb;
      fa[0] = f2bf(la[0]); fa[1] = f2bf(la[1]); fa[2] = f2bf(la[2]); fa[3] = f2bf(la[3]);
      fa[4] = f2bf(ha[0]); fa[5] = f2bf(ha[1]); fa[6] = f2bf(ha[2]); fa[7] = f2bf(ha[3]);
      fb[0] = f2bf(lb[0]); fb[1] = f2bf(lb[1]); fb[2] = f2bf(lb[2]); fb[3] = f2bf(lb[3]);
      fb[4] = f2bf(hb[0]); fb[5] = f2bf(hb[1]); fb[6] = f2bf(hb[2]); fb[7] = f2bf(hb[3]);
#pragma unroll
      for (int cg = 0; cg < 4; ++cg) {
        const short8 bfr = ldsB[(kk * 4 + cg) * 64 + lane];
        acc[0][cg] = __builtin_amdgcn_mfma_f32_16x16x32_bf16(fa, bfr, acc[0][cg], 0, 0, 0);
        acc[1][cg] = __builtin_amdgcn_mfma_f32_16x16x32_bf16(fb, bfr, acc[1][cg], 0, 0, 0);
      }
    }

    // D frag: col = lane&15, row = (lane>>4)*4 + r (m89-verified, matches R2-R5)
    float* yb = y + ((size_t)batch * kNodes + rows0) * kOut + colhalf * 64 + l15;
#pragma unroll
    for (int rt = 0; rt < 2; ++rt) {
#pragma unroll
      for (int cg = 0; cg < 4; ++cg) {
#pragma unroll
        for (int r = 0; r < 4; ++r) {
          const float v = acc[rt][cg][r] + blast;
          yb[(rt * 16 + l4 * 4 + r) * kOut + cg * 16] = v > 0.f ? v : 0.f;
        }
      }
    }
  }
}

}  // namespace

extern "C" void kernel_launch(void* const* d_in, const int* in_sizes, int n_in,
                              void* d_out, int out_size, void* d_ws, size_t ws_size,
                              hipStream_t stream) {
  const float* x    = (const float*)d_in[0];
  const float* mask = (const float*)d_in[1];
  const float* bias = (const float*)d_in[2];
  const int*   itab = (const int*)d_in[3];
  float*       y    = (float*)d_out;
  (void)in_sizes; (void)n_in; (void)out_size; (void)d_ws; (void)ws_size;

  prep_bfrag<<<dim3(32), dim3(256), 0, stream>>>(mask);
  tree_gemm<<<dim3(kGrid), dim3(kThreads), 0, stream>>>(x, bias, itab, y);
}

// Round 7
// 46.125 us; speedup vs baseline: 4.0236x; 1.5047x over previous
//
#include <hip/hip_runtime.h>
#include <hip/hip_bf16.h>

// TreeCnnLayer: y[b,l,o] = relu( sum_{k=0..3} x[b, idx[l,k], :] . mask[k,:,o] + bias[127] )
// == GEMM: A[131072 x 512] (gathered, fp32->bf16) * Bm[512 x 128] (mask), fp32 out.
//
// R7 = R4 (best so far, 50us) + T4 counted vmcnt + arithmetic gather indices.
//  - R4's loss: __syncthreads() drained vmcnt(0) every tile -> full gather latency
//    exposed 16x per block. Now: raw s_barrier + counted s_waitcnt vmcnt(N); the
//    next tile's global_load_lds stay in flight across both barriers (T3/T4).
//  - itab loads eliminated: heap indices are arithmetic (self v; parent (v-1)/2,
//    v=0 -> 8191; children 2v+1,2v+2 if 2v+1 < 8191 else 8191; row 8191 -> all 0).
//    Makes per-wave vmem sequence exactly [gll 8][stores 8][gll 8] -> vmcnt(16).
//  - stage/compute/epilogue verbatim from R4 (verified absmax 0.25).

namespace {

constexpr int kNodes = 8192;        // n+1 (n = 8191 = "null" row, also zero-idx pad row)
constexpr int kIn = 128;
constexpr int kOut = 128;
constexpr int kRowsPerTile = 16;
constexpr int kThreads = 256;
constexpr int kGrid = 512;
constexpr int kTilesPerBlock = 16;  // 256 rows per block; 512*256 = 131072 rows total

typedef __attribute__((ext_vector_type(8))) short short8;   // 8 bf16 (MFMA A/B frag)
typedef __attribute__((ext_vector_type(4))) float f32x4;

// bf16 B fragments: [kk(16)][colgrp(8)][lane(64)] of short8 = 128 KiB (L2-resident).
__device__ short8 g_bfrag[16 * 8 * 64];

__device__ __forceinline__ short f2bf(float f) {
  return __builtin_bit_cast(short, __float2bfloat16(f));  // RNE
}

template <int N>
__device__ __forceinline__ void waitvm() {
  asm volatile("s_waitcnt vmcnt(%0)" ::"n"(N) : "memory");
  __builtin_amdgcn_sched_barrier(0);
}

__device__ __forceinline__ void barrier() {
  __builtin_amdgcn_s_barrier();
  __builtin_amdgcn_sched_barrier(0);
}

// Prep: mask (4,128,128) fp32 -> bf16 MFMA-frag layout (proven R2-R6).
__global__ void prep_bfrag(const float* __restrict__ mask) {
  const int t = blockIdx.x * blockDim.x + threadIdx.x;
  const int kk = t >> 9, g = (t >> 6) & 7, lane = t & 63;
  const int krow = kk * 32 + (lane >> 4) * 8;
  const int col = g * 16 + (lane & 15);
  short8 pk;
#pragma unroll
  for (int e = 0; e < 8; ++e) pk[e] = f2bf(mask[(krow + e) * kOut + col]);
  g_bfrag[t] = pk;
}

__global__ __launch_bounds__(kThreads, 2)
void tree_gemm(const float* __restrict__ x, const float* __restrict__ bias,
               float* __restrict__ y) {
  // 2 buffers x 16 rows x 512 fp32 = 64 KiB
  __shared__ __align__(16) float ldsA[2][kRowsPerTile * 512];

  const int tid  = threadIdx.x;
  const int lane = tid & 63;
  const int wv   = tid >> 6;   // wave 0..3
  const int l15  = lane & 15;
  const int l4   = lane >> 4;  // 0..3
  const int lh   = lane >> 5;  // 0..1 (neighbor select within stage pair)
  const int l31  = lane & 31;

  const float blast = bias[kOut - 1];

  // ---- B fragments resident in VGPRs: wave wv owns colgrps {2wv, 2wv+1} ----
  short8 bfA[16], bfB[16];
  {
    const short8* gb = g_bfrag + wv * 2 * 64 + lane;
#pragma unroll
    for (int kk = 0; kk < 16; ++kk) {
      bfA[kk] = gb[kk * 512];
      bfB[kk] = gb[kk * 512 + 64];
    }
  }

  // XCD-chunked bijective swizzle (512 % 8 == 0)
  const int sb = (blockIdx.x & 7) * (kGrid / 8) + (blockIdx.x >> 3);
  const int bb = sb >> 5;                                             // batch 0..15
  const int blockRow0 = (sb & 31) * (kRowsPerTile * kTilesPerBlock);  // node base
  const float* xb = x + (size_t)bb * kNodes * kIn;

  // Stage tile t into buffer bufsel. inst m (=wv*8+j): row r=m>>1, half h=m&1.
  // Gather indices computed arithmetically (no loads): heap layout.
  // LDS linear dest: float m*256 + lane*4. Source pre-swizzled by (r&7) (rule #21);
  // read side XORs the same back. Verbatim R4 geometry (verified).
  auto stage = [&](int t, int bufsel) {
    const int lbase = blockRow0 + t * kRowsPerTile;
#pragma unroll
    for (int j = 0; j < 8; ++j) {
      const int m = wv * 8 + j;
      const int r = m >> 1, h = m & 1;           // h compile-time under unroll
      const int v = lbase + r;                   // wave-uniform node id
      int e0, e1;
      if (h == 0) {                              // {self, parent}
        e0 = v;
        e1 = (v > 0) ? ((v - 1) >> 1) : (kNodes - 1);
      } else {                                   // {child0, child1}
        const int f = 2 * v + 1;
        const bool ok = f < (kNodes - 1);
        e0 = ok ? f : (kNodes - 1);
        e1 = ok ? f + 1 : (kNodes - 1);
      }
      if (v == kNodes - 1) { e0 = 0; e1 = 0; }   // pad row of tab is all-zero
      const int gi = lh ? e1 : e0;
      const float* src = xb + (size_t)gi * kIn + ((l31 ^ (r & 7)) << 2);
      float* dst = &ldsA[bufsel][m * 256];       // wave-uniform base; HW adds lane*16
      __builtin_amdgcn_global_load_lds(
          (const __attribute__((address_space(1))) void*)src,
          (__attribute__((address_space(3))) void*)dst, 16, 0, 0);
    }
  };

  // Compute tile t from buf (16 rows x 128 cols), fused bias+relu store.
  auto compute = [&](int t) {
    const float* buf = ldsA[t & 1];
    f32x4 acc0 = {}, acc1 = {};
#pragma unroll
    for (int kk = 0; kk < 16; ++kk) {
      const int s0 = kk * 8 + ((l4 * 2) ^ (l15 & 7));
      const int s1 = kk * 8 + ((l4 * 2 + 1) ^ (l15 & 7));
      const f32x4 lo = *reinterpret_cast<const f32x4*>(buf + l15 * 512 + s0 * 4);
      const f32x4 hi = *reinterpret_cast<const f32x4*>(buf + l15 * 512 + s1 * 4);
      short8 a;
      a[0] = f2bf(lo[0]); a[1] = f2bf(lo[1]); a[2] = f2bf(lo[2]); a[3] = f2bf(lo[3]);
      a[4] = f2bf(hi[0]); a[5] = f2bf(hi[1]); a[6] = f2bf(hi[2]); a[7] = f2bf(hi[3]);
      acc0 = __builtin_amdgcn_mfma_f32_16x16x32_bf16(a, bfA[kk], acc0, 0, 0, 0);
      acc1 = __builtin_amdgcn_mfma_f32_16x16x32_bf16(a, bfB[kk], acc1, 0, 0, 0);
    }
    // D frag: col = lane&15, row = (lane>>4)*4 + r (m89-verified)
    const int lbase = blockRow0 + t * kRowsPerTile;
    float* yb = y + ((size_t)bb * kNodes + lbase) * kOut;
    const int oc = wv * 32 + l15;
#pragma unroll
    for (int r = 0; r < 4; ++r) {
      const float v0 = acc0[r] + blast;
      const float v1 = acc1[r] + blast;
      yb[(l4 * 4 + r) * kOut + oc]      = v0 > 0.f ? v0 : 0.f;
      yb[(l4 * 4 + r) * kOut + oc + 16] = v1 > 0.f ? v1 : 0.f;
    }
  };

  // ---- pipeline: ring-2, counted vmcnt, 2 raw barriers/iter, no vm drain ----
  stage(0, 0);

  // t = 0: outstanding [bfrag?][gll0 8][gll1 8] -> vmcnt(8) retires gll0 (+prologue)
  stage(1, 1);
  waitvm<8>();
  barrier();
  compute(0);
  barrier();

  for (int t = 1; t < 15; ++t) {
    stage(t + 1, (t + 1) & 1);
    // outstanding: [gll(t) 8][stores(t-1) 8][gll(t+1) 8] = 24 -> vmcnt(16)
    waitvm<16>();
    barrier();
    compute(t);
    barrier();
  }

  // t = 15: outstanding [gll15 8][stores14 8] -> vmcnt(8)
  waitvm<8>();
  barrier();
  compute(15);
}

}  // namespace

extern "C" void kernel_launch(void* const* d_in, const int* in_sizes, int n_in,
                              void* d_out, int out_size, void* d_ws, size_t ws_size,
                              hipStream_t stream) {
  const float* x    = (const float*)d_in[0];
  const float* mask = (const float*)d_in[1];
  const float* bias = (const float*)d_in[2];
  float*       y    = (float*)d_out;
  (void)in_sizes; (void)n_in; (void)out_size; (void)d_ws; (void)ws_size;

  prep_bfrag<<<dim3(32), dim3(256), 0, stream>>>(mask);
  tree_gemm<<<dim3(kGrid), dim3(kThreads), 0, stream>>>(x, bias, y);
}